// Round 4
// baseline (156.628 us; speedup 1.0000x reference)
//
#include <hip/hip_runtime.h>
#include <cstdint>

#define N_SEQ 8
#define B_DIM 64
#define H_DIM 128
#define F_DIM 256
#define HS 64

typedef __attribute__((ext_vector_type(8))) short short8;
typedef __attribute__((ext_vector_type(4))) float floatx4;

__device__ __forceinline__ ushort f2bf(float f) {
    union { float f; uint32_t u; } v; v.f = f;
    uint32_t r = v.u + 0x7FFF + ((v.u >> 16) & 1);   // RNE
    return (ushort)(r >> 16);
}

// async 16B-per-lane global -> LDS (wave-uniform LDS base + lane*16)
__device__ __forceinline__ void async_ld16(const ushort* g, ushort* lds) {
    __builtin_amdgcn_global_load_lds(
        (const __attribute__((address_space(1))) unsigned int*)g,
        (__attribute__((address_space(3))) unsigned int*)lds,
        16, 0, 0);
}

// ---------------- W transpose + cast: Wtb[n=192][k=256] bf16 ----------------
__global__ __launch_bounds__(256) void prep_w(
    const float* __restrict__ Wq, const float* __restrict__ Wk,
    const float* __restrict__ Wv, ushort* __restrict__ Wtb)
{
    const int n = blockIdx.x;                 // 0..191
    const float* W = (n < 64) ? Wq : (n < 128) ? Wk : Wv;
    const int c = n & 63;
    const int k = threadIdx.x;                // 0..255
    Wtb[n * 256 + k] = f2bf(W[k * 64 + c]);
}

// ---------------- QKV projection via MFMA (round-0 form, unchanged) --------
#define XS_STRIDE 264   // 256 + 8 pad (bf16 elems)
__global__ __launch_bounds__(256, 4) void proj_mfma(
    const float* __restrict__ x, const ushort* __restrict__ Wtb,
    ushort* __restrict__ Qb, ushort* __restrict__ Kb, ushort* __restrict__ Vtb)
{
    __shared__ ushort xs[64 * XS_STRIDE];     // 33,792 B
    const int t = threadIdx.x;
    const int blk = blockIdx.x;
    const int64_t row0 = (int64_t)blk * 64;

    const float4* xg = (const float4*)(x + row0 * F_DIM);
    #pragma unroll
    for (int u = 0; u < 8; ++u) {
        const int idx = t + 256 * u;
        const int row = idx >> 5;
        const int c8 = (idx & 31) * 8;
        const float4 a = xg[idx * 2];
        const float4 b = xg[idx * 2 + 1];
        *(ushort4*)&xs[row * XS_STRIDE + c8] =
            make_ushort4(f2bf(a.x), f2bf(a.y), f2bf(a.z), f2bf(a.w));
        *(ushort4*)&xs[row * XS_STRIDE + c8 + 4] =
            make_ushort4(f2bf(b.x), f2bf(b.y), f2bf(b.z), f2bf(b.w));
    }
    __syncthreads();

    const int w = t >> 6, lane = t & 63;
    const int q16 = lane >> 4, l16 = lane & 15;
    const int n0 = w * 48;

    floatx4 acc[4][3];
    #pragma unroll
    for (int mt = 0; mt < 4; ++mt)
        #pragma unroll
        for (int nt = 0; nt < 3; ++nt) acc[mt][nt] = (floatx4){0.f, 0.f, 0.f, 0.f};

    short8 nb[3];
    #pragma unroll
    for (int nt = 0; nt < 3; ++nt)
        nb[nt] = *(const short8*)&Wtb[(n0 + nt * 16 + l16) * 256 + q16 * 8];

    for (int ks = 0; ks < 8; ++ks) {
        short8 cur[3];
        #pragma unroll
        for (int nt = 0; nt < 3; ++nt) cur[nt] = nb[nt];
        if (ks < 7) {
            #pragma unroll
            for (int nt = 0; nt < 3; ++nt)
                nb[nt] = *(const short8*)&Wtb[(n0 + nt * 16 + l16) * 256 + (ks + 1) * 32 + q16 * 8];
        }
        #pragma unroll
        for (int mt = 0; mt < 4; ++mt) {
            const short8 afr = *(const short8*)&xs[(mt * 16 + l16) * XS_STRIDE + ks * 32 + q16 * 8];
            #pragma unroll
            for (int nt = 0; nt < 3; ++nt)
                acc[mt][nt] = __builtin_amdgcn_mfma_f32_16x16x32_bf16(afr, cur[nt], acc[mt][nt], 0, 0, 0);
        }
    }

    const float qscale = 0.0625f * 1.44269504f;
    #pragma unroll
    for (int mt = 0; mt < 4; ++mt) {
        const int64_t g = row0 + mt * 16 + q16 * 4;
        #pragma unroll
        for (int nt = 0; nt < 3; ++nt) {
            const int ntb = n0 + nt * 16;             // wave-uniform
            const int n = ntb + l16;
            if (ntb < 64) {
                #pragma unroll
                for (int r = 0; r < 4; ++r)
                    Qb[(g + r) * 64 + n] = f2bf(acc[mt][nt][r] * qscale);
            } else if (ntb < 128) {
                #pragma unroll
                for (int r = 0; r < 4; ++r)
                    Kb[(g + r) * 64 + (n - 64)] = f2bf(acc[mt][nt][r]);
            } else {
                const int d = n - 128;
                const int ib = (int)(g >> 7);
                const int h = (int)(g & 127);
                *(ushort4*)&Vtb[((int64_t)(ib * 64 + d)) * 128 + h] =
                    make_ushort4(f2bf(acc[mt][nt][0]), f2bf(acc[mt][nt][1]),
                                 f2bf(acc[mt][nt][2]), f2bf(acc[mt][nt][3]));
            }
        }
    }
}

// ---------------- attention ------------------------------------------------
// 512 blocks (one per jb, 2/CU). K: async global_load_lds double-buffer
// (frag-linear, 8 frags x 1 KB per buf... 16 frags). V: DIRECT global->reg
// (identity mapping of the old staged layout; V tiles are L2-resident on
// this XCD thanks to the XCD-major b swizzle). Loads issued right after the
// barrier, consumed after KQ^T+softmax (~800 cyc) -> L2 latency covered.
// Deferred normalization: P packed unnormalized; of += tmp*inv per i.
#define PT_STRIDE 40    // 32 + 8 pad (80 B rows, 16B-aligned b128 reads)
__global__ __launch_bounds__(256, 2) void attn_mfma(
    const ushort* __restrict__ Qb, const ushort* __restrict__ Kb,
    const ushort* __restrict__ Vtb, float* __restrict__ out)
{
    __shared__ ushort Ks[2][8192];            // 2 x 16 KB, frag-linear
    __shared__ ushort Ps[4][2][16 * PT_STRIDE];  // 10,240 B

    const int t = threadIdx.x;
    const int blk = blockIdx.x;
    const int b  = ((blk & 7) << 3) | ((blk >> 3) & 7);   // XCD-major b
    const int j  = blk >> 6;
    const int jb = j * 64 + b;

    const int w = t >> 6, lane = t & 63;
    const int q16 = lane >> 4, l16 = lane & 15;

    int koff[4], ldsoff[4];
    #pragma unroll
    for (int u = 0; u < 4; ++u) {
        const int fi = w * 4 + u;
        koff[u] = ((fi & 7) * 16 + l16) * 64 + (fi >> 3) * 32 + q16 * 8;
        ldsoff[u] = fi * 512;   // ushorts
    }
    const int voff0 = l16 * 128 + q16 * 8;    // V direct-read lane base

    // Q B-frags for both halves (Qb pre-scaled by log2e/16)
    const int prow = jb * H_DIM + w * 16 + l16;
    short8 qa[2][2];
    #pragma unroll
    for (int hh = 0; hh < 2; ++hh)
        #pragma unroll
        for (int ks = 0; ks < 2; ++ks)
            qa[hh][ks] = *(const short8*)&Qb[(prow + hh * 64) * 64 + ks * 32 + q16 * 8];

    floatx4 of[2][4];
    #pragma unroll
    for (int hh = 0; hh < 2; ++hh)
        #pragma unroll
        for (int mt = 0; mt < 4; ++mt) of[hh][mt] = (floatx4){0.f, 0.f, 0.f, 0.f};

    // ---- prologue: stage K tile 0 into buffer 0 ----
    {
        const ushort* kg = Kb + ((0 * B_DIM + b) << 13);
        #pragma unroll
        for (int u = 0; u < 4; ++u) {
            const int lo = __builtin_amdgcn_readfirstlane(ldsoff[u]);
            async_ld16(kg + koff[u], &Ks[0][lo]);
        }
    }

    for (int i = 0; i < N_SEQ; ++i) {
        const int buf = i & 1;
        __syncthreads();   // drains stage(i) loads; protects buf's prior readers

        if (i < N_SEQ - 1) {   // async stage of K tile i+1; lands during compute
            const ushort* kg = Kb + (((i + 1) * B_DIM + b) << 13);
            #pragma unroll
            for (int u = 0; u < 4; ++u) {
                const int lo = __builtin_amdgcn_readfirstlane(ldsoff[u]);
                async_ld16(kg + koff[u], &Ks[buf ^ 1][lo]);
            }
        }

        // ---- V tile i: direct global->reg, issue-early (consumed post-softmax)
        const ushort* vg = Vtb + ((i * B_DIM + b) << 13);
        short8 av[4][4];
        #pragma unroll
        for (int kq = 0; kq < 4; ++kq)
            #pragma unroll
            for (int mt = 0; mt < 4; ++mt)
                av[kq][mt] = *(const short8*)&vg[voff0 + mt * 2048 + kq * 32];

        // ---- S^T = K Q^T for both p-halves, sharing K frags ----
        floatx4 sf[2][8];
        #pragma unroll
        for (int hh = 0; hh < 2; ++hh)
            #pragma unroll
            for (int nt = 0; nt < 8; ++nt) sf[hh][nt] = (floatx4){0.f, 0.f, 0.f, 0.f};
        #pragma unroll
        for (int ks = 0; ks < 2; ++ks)
            #pragma unroll
            for (int nt = 0; nt < 8; ++nt) {
                const short8 ak = *(const short8*)&Ks[buf][(ks * 8 + nt) * 512 + lane * 8];
                sf[0][nt] = __builtin_amdgcn_mfma_f32_16x16x32_bf16(ak, qa[0][ks], sf[0][nt], 0, 0, 0);
                sf[1][nt] = __builtin_amdgcn_mfma_f32_16x16x32_bf16(ak, qa[1][ks], sf[1][nt], 0, 0, 0);
            }

        // ---- softmax along q: exp2 + sum; inv consumed only at i-end ----
        float inv[2];
        #pragma unroll
        for (int hh = 0; hh < 2; ++hh) {
            float l = 0.f;
            #pragma unroll
            for (int nt = 0; nt < 8; ++nt)
                #pragma unroll
                for (int r = 0; r < 4; ++r) {
                    sf[hh][nt][r] = __builtin_amdgcn_exp2f(sf[hh][nt][r]);
                    l += sf[hh][nt][r];
                }
            l += __shfl_xor(l, 16);
            l += __shfl_xor(l, 32);
            inv[hh] = __builtin_amdgcn_rcpf(l);
        }

        // ---- O^T += V^T P^T, kq-chunked; P packed UNNORMALIZED ----
        floatx4 tmp[2][4];
        #pragma unroll
        for (int hh = 0; hh < 2; ++hh)
            #pragma unroll
            for (int mt = 0; mt < 4; ++mt) tmp[hh][mt] = (floatx4){0.f, 0.f, 0.f, 0.f};

        #pragma unroll
        for (int kq = 0; kq < 4; ++kq) {
            #pragma unroll
            for (int hh = 0; hh < 2; ++hh)
                #pragma unroll
                for (int tt = 0; tt < 2; ++tt) {
                    const int nt = kq * 2 + tt;
                    *(ushort4*)&Ps[w][hh][l16 * PT_STRIDE + tt * 16 + q16 * 4] =
                        make_ushort4(f2bf(sf[hh][nt][0]), f2bf(sf[hh][nt][1]),
                                     f2bf(sf[hh][nt][2]), f2bf(sf[hh][nt][3]));
                }
            const short8 bp0 = *(const short8*)&Ps[w][0][l16 * PT_STRIDE + q16 * 8];
            const short8 bp1 = *(const short8*)&Ps[w][1][l16 * PT_STRIDE + q16 * 8];
            #pragma unroll
            for (int mt = 0; mt < 4; ++mt) {
                tmp[0][mt] = __builtin_amdgcn_mfma_f32_16x16x32_bf16(av[kq][mt], bp0, tmp[0][mt], 0, 0, 0);
                tmp[1][mt] = __builtin_amdgcn_mfma_f32_16x16x32_bf16(av[kq][mt], bp1, tmp[1][mt], 0, 0, 0);
            }
        }

        #pragma unroll
        for (int hh = 0; hh < 2; ++hh)
            #pragma unroll
            for (int mt = 0; mt < 4; ++mt)
                #pragma unroll
                for (int r = 0; r < 4; ++r)
                    of[hh][mt][r] += tmp[hh][mt][r] * inv[hh];
    }

    // ---- epilogue: O^T C-layout -> float4 stores (4 consecutive d) ----
    #pragma unroll
    for (int hh = 0; hh < 2; ++hh)
        #pragma unroll
        for (int mt = 0; mt < 4; ++mt)
            *(float4*)&out[(int64_t)(prow + hh * 64) * HS + mt * 16 + q16 * 4] =
                make_float4(of[hh][mt][0], of[hh][mt][1], of[hh][mt][2], of[hh][mt][3]);
}

extern "C" void kernel_launch(void* const* d_in, const int* in_sizes, int n_in,
                              void* d_out, int out_size, void* d_ws, size_t ws_size,
                              hipStream_t stream)
{
    const float* x  = (const float*)d_in[0];
    const float* Wq = (const float*)d_in[1];
    const float* Wk = (const float*)d_in[2];
    const float* Wv = (const float*)d_in[3];
    float* out = (float*)d_out;

    const size_t qkv = (size_t)N_SEQ * B_DIM * H_DIM * HS;   // 4,194,304 elems
    ushort* Qb  = (ushort*)d_ws;
    ushort* Kb  = Qb + qkv;
    ushort* Vtb = Kb + qkv;
    ushort* Wtb = Vtb + qkv;                                 // 192*256 elems

    prep_w<<<192, 256, 0, stream>>>(Wq, Wk, Wv, Wtb);
    proj_mfma<<<(N_SEQ * B_DIM * H_DIM) / 64, 256, 0, stream>>>(x, Wtb, Qb, Kb, Vtb);
    attn_mfma<<<N_SEQ * B_DIM, 256, 0, stream>>>(Qb, Kb, Vtb, out);
}

// Round 5
// 142.124 us; speedup vs baseline: 1.1020x; 1.1020x over previous
//
#include <hip/hip_runtime.h>
#include <cstdint>

#define N_SEQ 8
#define B_DIM 64
#define H_DIM 128
#define F_DIM 256
#define HS 64

typedef __attribute__((ext_vector_type(8))) short short8;
typedef __attribute__((ext_vector_type(4))) float floatx4;

__device__ __forceinline__ ushort f2bf(float f) {
    union { float f; uint32_t u; } v; v.f = f;
    uint32_t r = v.u + 0x7FFF + ((v.u >> 16) & 1);   // RNE
    return (ushort)(r >> 16);
}

// async 16B-per-lane global -> LDS (wave-uniform LDS base + lane*16)
__device__ __forceinline__ void async_ld16(const ushort* g, ushort* lds) {
    __builtin_amdgcn_global_load_lds(
        (const __attribute__((address_space(1))) unsigned int*)g,
        (__attribute__((address_space(3))) unsigned int*)lds,
        16, 0, 0);
}

// ---------------- W transpose + cast: Wtb[n=192][k=256] bf16 ----------------
__global__ __launch_bounds__(256) void prep_w(
    const float* __restrict__ Wq, const float* __restrict__ Wk,
    const float* __restrict__ Wv, ushort* __restrict__ Wtb)
{
    const int n = blockIdx.x;                 // 0..191
    const float* W = (n < 64) ? Wq : (n < 128) ? Wk : Wv;
    const int c = n & 63;
    const int k = threadIdx.x;                // 0..255
    Wtb[n * 256 + k] = f2bf(W[k * 64 + c]);
}

// ---------------- QKV projection via MFMA (round-3 form, unchanged) --------
#define XS_STRIDE 264   // 256 + 8 pad (bf16 elems)
__global__ __launch_bounds__(256, 4) void proj_mfma(
    const float* __restrict__ x, const ushort* __restrict__ Wtb,
    ushort* __restrict__ Qb, ushort* __restrict__ Kb, ushort* __restrict__ Vtb)
{
    __shared__ ushort xs[64 * XS_STRIDE];     // 33,792 B
    const int t = threadIdx.x;
    const int blk = blockIdx.x;
    const int64_t row0 = (int64_t)blk * 64;

    const float4* xg = (const float4*)(x + row0 * F_DIM);
    #pragma unroll
    for (int u = 0; u < 8; ++u) {
        const int idx = t + 256 * u;
        const int row = idx >> 5;
        const int c8 = (idx & 31) * 8;
        const float4 a = xg[idx * 2];
        const float4 b = xg[idx * 2 + 1];
        *(ushort4*)&xs[row * XS_STRIDE + c8] =
            make_ushort4(f2bf(a.x), f2bf(a.y), f2bf(a.z), f2bf(a.w));
        *(ushort4*)&xs[row * XS_STRIDE + c8 + 4] =
            make_ushort4(f2bf(b.x), f2bf(b.y), f2bf(b.z), f2bf(b.w));
    }
    __syncthreads();

    const int w = t >> 6, lane = t & 63;
    const int q16 = lane >> 4, l16 = lane & 15;
    const int n0 = w * 48;

    floatx4 acc[4][3];
    #pragma unroll
    for (int mt = 0; mt < 4; ++mt)
        #pragma unroll
        for (int nt = 0; nt < 3; ++nt) acc[mt][nt] = (floatx4){0.f, 0.f, 0.f, 0.f};

    short8 nb[3];
    #pragma unroll
    for (int nt = 0; nt < 3; ++nt)
        nb[nt] = *(const short8*)&Wtb[(n0 + nt * 16 + l16) * 256 + q16 * 8];

    for (int ks = 0; ks < 8; ++ks) {
        short8 cur[3];
        #pragma unroll
        for (int nt = 0; nt < 3; ++nt) cur[nt] = nb[nt];
        if (ks < 7) {
            #pragma unroll
            for (int nt = 0; nt < 3; ++nt)
                nb[nt] = *(const short8*)&Wtb[(n0 + nt * 16 + l16) * 256 + (ks + 1) * 32 + q16 * 8];
        }
        #pragma unroll
        for (int mt = 0; mt < 4; ++mt) {
            const short8 afr = *(const short8*)&xs[(mt * 16 + l16) * XS_STRIDE + ks * 32 + q16 * 8];
            #pragma unroll
            for (int nt = 0; nt < 3; ++nt)
                acc[mt][nt] = __builtin_amdgcn_mfma_f32_16x16x32_bf16(afr, cur[nt], acc[mt][nt], 0, 0, 0);
        }
    }

    const float qscale = 0.0625f * 1.44269504f;
    #pragma unroll
    for (int mt = 0; mt < 4; ++mt) {
        const int64_t g = row0 + mt * 16 + q16 * 4;
        #pragma unroll
        for (int nt = 0; nt < 3; ++nt) {
            const int ntb = n0 + nt * 16;             // wave-uniform
            const int n = ntb + l16;
            if (ntb < 64) {
                #pragma unroll
                for (int r = 0; r < 4; ++r)
                    Qb[(g + r) * 64 + n] = f2bf(acc[mt][nt][r] * qscale);
            } else if (ntb < 128) {
                #pragma unroll
                for (int r = 0; r < 4; ++r)
                    Kb[(g + r) * 64 + (n - 64)] = f2bf(acc[mt][nt][r]);
            } else {
                const int d = n - 128;
                const int ib = (int)(g >> 7);
                const int h = (int)(g & 127);
                *(ushort4*)&Vtb[((int64_t)(ib * 64 + d)) * 128 + h] =
                    make_ushort4(f2bf(acc[mt][nt][0]), f2bf(acc[mt][nt][1]),
                                 f2bf(acc[mt][nt][2]), f2bf(acc[mt][nt][3]));
            }
        }
    }
}

// ---------------- attention: half-tiles, 8 waves, 4 waves/SIMD -------------
// 512 blocks (j,b), 512 threads. Each wave owns ONE p-16-group (w*16+l16).
// K/V tiles split into k-halves of 64 (16 substeps); async global_load_lds
// double-buffer (8 frags x 1 KB per half; wave w stages K frag w + V frag w).
// LDS = 16K (Ks) + 16K (Vt) + 10K (Ps) = 43,008 B -> 2 blocks/CU = 16
// waves/CU = 4 waves/SIMD (2x round-3 TLP; kernel is latency-bound).
// Deferred normalization: lsum/tmp accumulate across both halves; one
// inv + of += tmp*inv per i. Same math/order as round 3.
#define PT_STRIDE 40    // 32 + 8 pad (80 B rows, 16B-aligned b128 reads)
__global__ __launch_bounds__(512, 4) void attn_mfma(
    const ushort* __restrict__ Qb, const ushort* __restrict__ Kb,
    const ushort* __restrict__ Vtb, float* __restrict__ out)
{
    __shared__ ushort Ks[2][4096];            // 2 x 8 KB, frag-linear (8 frags)
    __shared__ ushort Vt[2][4096];            // 2 x 8 KB, frag-linear (8 frags)
    __shared__ ushort Ps[8][16 * PT_STRIDE];  // 10,240 B (per-wave, 1 hh)

    const int t = threadIdx.x;
    const int blk = blockIdx.x;
    const int b  = ((blk & 7) << 3) | ((blk >> 3) & 7);   // XCD-major b
    const int j  = blk >> 6;
    const int jb = j * 64 + b;

    const int w = t >> 6, lane = t & 63;      // w = 0..7
    const int q16 = lane >> 4, l16 = lane & 15;

    // staging: wave w stages K frag w and V frag w of the current half-tile.
    // K frag fi: k-row (fi&3)*16+l16 (of the half), d-off (fi>>2)*32+q16*8
    // V frag fi: d-row (fi&3)*16+l16, k-off (fi>>2)*32+q16*8 (within half)
    const int koff0 = ((w & 3) * 16 + l16) * 64 + (w >> 2) * 32 + q16 * 8;
    const int voff0 = ((w & 3) * 16 + l16) * 128 + (w >> 2) * 32 + q16 * 8;
    const int lo = __builtin_amdgcn_readfirstlane(w * 512);   // frag-linear dest

    // Q B-frags for this wave's p-group (Qb pre-scaled by log2e/16)
    const int prow = jb * H_DIM + w * 16 + l16;
    short8 qa[2];
    #pragma unroll
    for (int ks = 0; ks < 2; ++ks)
        qa[ks] = *(const short8*)&Qb[prow * 64 + ks * 32 + q16 * 8];

    floatx4 of[4];
    #pragma unroll
    for (int mt = 0; mt < 4; ++mt) of[mt] = (floatx4){0.f, 0.f, 0.f, 0.f};

    // ---- prologue: stage half-tile (i=0, s=0) into buffer 0 ----
    {
        const ushort* kg = Kb + ((0 * B_DIM + b) << 13);
        const ushort* vg = Vtb + ((0 * B_DIM + b) << 13);
        async_ld16(kg + koff0, &Ks[0][lo]);
        async_ld16(vg + voff0, &Vt[0][lo]);
    }

    for (int i = 0; i < N_SEQ; ++i) {
        float lsum = 0.f;
        floatx4 tmp[4];
        #pragma unroll
        for (int mt = 0; mt < 4; ++mt) tmp[mt] = (floatx4){0.f, 0.f, 0.f, 0.f};

        #pragma unroll
        for (int s = 0; s < 2; ++s) {
            const int step = i * 2 + s;
            const int buf = step & 1;
            __syncthreads();   // drains stage(step); protects buf's prior readers

            if (step < 2 * N_SEQ - 1) {   // stage next half-tile during compute
                const int i2 = (step + 1) >> 1, s2 = (step + 1) & 1;
                const ushort* kg = Kb + ((i2 * B_DIM + b) << 13) + s2 * 4096;
                const ushort* vg = Vtb + ((i2 * B_DIM + b) << 13) + s2 * 64;
                async_ld16(kg + koff0, &Ks[buf ^ 1][lo]);
                async_ld16(vg + voff0, &Vt[buf ^ 1][lo]);
            }

            // ---- S^T = K Q^T on this k-half (4 nt groups of 16 k) ----
            floatx4 sf[4];
            #pragma unroll
            for (int nt = 0; nt < 4; ++nt) sf[nt] = (floatx4){0.f, 0.f, 0.f, 0.f};
            #pragma unroll
            for (int ks = 0; ks < 2; ++ks)
                #pragma unroll
                for (int nt = 0; nt < 4; ++nt) {
                    const short8 ak = *(const short8*)&Ks[buf][(ks * 4 + nt) * 512 + lane * 8];
                    sf[nt] = __builtin_amdgcn_mfma_f32_16x16x32_bf16(ak, qa[ks], sf[nt], 0, 0, 0);
                }

            // ---- exp2 + lane-local partial sum ----
            #pragma unroll
            for (int nt = 0; nt < 4; ++nt)
                #pragma unroll
                for (int r = 0; r < 4; ++r) {
                    sf[nt][r] = __builtin_amdgcn_exp2f(sf[nt][r]);
                    lsum += sf[nt][r];
                }

            // ---- PV on this half: P packed UNNORMALIZED, kq-chunked ----
            #pragma unroll
            for (int kq = 0; kq < 2; ++kq) {
                #pragma unroll
                for (int tt = 0; tt < 2; ++tt) {
                    const int nt = kq * 2 + tt;
                    *(ushort4*)&Ps[w][l16 * PT_STRIDE + tt * 16 + q16 * 4] =
                        make_ushort4(f2bf(sf[nt][0]), f2bf(sf[nt][1]),
                                     f2bf(sf[nt][2]), f2bf(sf[nt][3]));
                }
                const short8 bp = *(const short8*)&Ps[w][l16 * PT_STRIDE + q16 * 8];
                #pragma unroll
                for (int mt = 0; mt < 4; ++mt) {
                    const short8 av = *(const short8*)&Vt[buf][(kq * 4 + mt) * 512 + lane * 8];
                    tmp[mt] = __builtin_amdgcn_mfma_f32_16x16x32_bf16(av, bp, tmp[mt], 0, 0, 0);
                }
            }
        }

        // ---- per-i: cross-quad sum, one rcp, deferred normalization ----
        lsum += __shfl_xor(lsum, 16);
        lsum += __shfl_xor(lsum, 32);
        const float inv = __builtin_amdgcn_rcpf(lsum);
        #pragma unroll
        for (int mt = 0; mt < 4; ++mt)
            #pragma unroll
            for (int r = 0; r < 4; ++r)
                of[mt][r] += tmp[mt][r] * inv;
    }

    // ---- epilogue: O^T C-layout -> float4 stores (4 consecutive d) ----
    #pragma unroll
    for (int mt = 0; mt < 4; ++mt)
        *(float4*)&out[(int64_t)prow * HS + mt * 16 + q16 * 4] =
            make_float4(of[mt][0], of[mt][1], of[mt][2], of[mt][3]);
}

extern "C" void kernel_launch(void* const* d_in, const int* in_sizes, int n_in,
                              void* d_out, int out_size, void* d_ws, size_t ws_size,
                              hipStream_t stream)
{
    const float* x  = (const float*)d_in[0];
    const float* Wq = (const float*)d_in[1];
    const float* Wk = (const float*)d_in[2];
    const float* Wv = (const float*)d_in[3];
    float* out = (float*)d_out;

    const size_t qkv = (size_t)N_SEQ * B_DIM * H_DIM * HS;   // 4,194,304 elems
    ushort* Qb  = (ushort*)d_ws;
    ushort* Kb  = Qb + qkv;
    ushort* Vtb = Kb + qkv;
    ushort* Wtb = Vtb + qkv;                                 // 192*256 elems

    prep_w<<<192, 256, 0, stream>>>(Wq, Wk, Wv, Wtb);
    proj_mfma<<<(N_SEQ * B_DIM * H_DIM) / 64, 256, 0, stream>>>(x, Wtb, Qb, Kb, Vtb);
    attn_mfma<<<N_SEQ * B_DIM, 512, 0, stream>>>(Qb, Kb, Vtb, out);
}